// Round 2
// baseline (1850.822 us; speedup 1.0000x reference)
//
#include <hip/hip_runtime.h>
#include <math.h>

#define NTOT   64000
#define NNODE  1000
#define NBATCH 64
#define NSEQ   12
#define NFEAT  4
#define NCH    48
#define NE     1024000
#define HH1    256
#define HH2    128

__device__ __forceinline__ float lrelu(float x){ return x > 0.f ? x : 0.2f*x; }
__device__ __forceinline__ float sigmoidf_(float x){ return 1.f/(1.f+__expf(-x)); }

// ---------------- GAT: h = x @ W_gat, per-node attention scalars ----------------
__global__ void __launch_bounds__(256) k_gat_h(const float* __restrict__ x, const float* __restrict__ Wg,
                       const float* __restrict__ att_s, const float* __restrict__ att_d,
                       float* __restrict__ hfeat, float* __restrict__ asrc, float* __restrict__ adst){
  __shared__ __align__(16) float Ws[48*96];
  __shared__ float as_s[96], ad_s[96];
  for (int i = threadIdx.x; i < 48*96; i += 256) Ws[i] = Wg[i];
  if (threadIdx.x < 96){ as_s[threadIdx.x] = att_s[threadIdx.x]; ad_s[threadIdx.x] = att_d[threadIdx.x]; }
  __syncthreads();
  int n = blockIdx.x * 256 + threadIdx.x;
  if (n >= NTOT) return;
  float xr[48];
  const float4* xv = (const float4*)(x + (size_t)n*48);
  #pragma unroll
  for (int q = 0; q < 12; ++q){ float4 v = xv[q]; xr[q*4]=v.x; xr[q*4+1]=v.y; xr[q*4+2]=v.z; xr[q*4+3]=v.w; }
  float a0=0.f,a1=0.f,d0=0.f,d1=0.f;
  float* hrow = hfeat + (size_t)n*96;
  for (int j = 0; j < 96; ++j){
    float acc = 0.f;
    #pragma unroll
    for (int k = 0; k < 48; ++k) acc += xr[k]*Ws[k*96+j];
    hrow[j] = acc;
    if (j < 48){ a0 += acc*as_s[j]; d0 += acc*ad_s[j]; }
    else       { a1 += acc*as_s[j]; d1 += acc*ad_s[j]; }
  }
  asrc[n*2]=a0; asrc[n*2+1]=a1; adst[n*2]=d0; adst[n*2+1]=d1;
}

// ---------------- CSR build ----------------
__global__ void k_count(const int* __restrict__ ei, int* __restrict__ cnt){
  int e = blockIdx.x*256 + threadIdx.x;
  if (e < NE) atomicAdd(&cnt[ei[NE + e]], 1);
}

__global__ void __launch_bounds__(1024) k_scan(const int* __restrict__ cnt, int* __restrict__ offs,
                                               int* __restrict__ cursor, int n){
  __shared__ int tmp[1024];
  __shared__ int carry;
  if (threadIdx.x == 0) carry = 0;
  __syncthreads();
  for (int base = 0; base < n; base += 1024){
    int i = base + (int)threadIdx.x;
    int v = (i < n) ? cnt[i] : 0;
    tmp[threadIdx.x] = v; __syncthreads();
    for (int d = 1; d < 1024; d <<= 1){
      int t = (threadIdx.x >= d) ? tmp[threadIdx.x - d] : 0;
      __syncthreads();
      tmp[threadIdx.x] += t;
      __syncthreads();
    }
    int excl = tmp[threadIdx.x] - v;
    int total = tmp[1023];
    if (i < n){ int o = carry + excl; offs[i] = o; cursor[i] = o; }
    __syncthreads();
    if (threadIdx.x == 0) carry += total;
    __syncthreads();
  }
  if (threadIdx.x == 0) offs[n] = carry;
}

__global__ void k_scatter(const int* __restrict__ ei, int* __restrict__ cursor, int* __restrict__ csr){
  int e = blockIdx.x*256 + threadIdx.x;
  if (e < NE){
    int d = ei[NE + e], s = ei[e];
    int pos = atomicAdd(&cursor[d], 1);
    csr[pos] = s;
  }
}

// ---------------- per-node softmax + aggregation + scatter into x_seq ----------------
__global__ void __launch_bounds__(256) k_node(const float* __restrict__ hfeat, const float* __restrict__ asrc,
                      const float* __restrict__ adst, const int* __restrict__ offs,
                      const int* __restrict__ csr, const float* __restrict__ bias,
                      float* __restrict__ xseq){
  __shared__ float gsh[4][96];
  int wv = threadIdx.x >> 6, lane = threadIdx.x & 63;
  int n = blockIdx.x*4 + wv;
  int off = offs[n], deg = offs[n+1] - off;
  float ad0 = adst[n*2], ad1 = adst[n*2+1];
  float es0 = lrelu(asrc[n*2] + ad0);
  float es1 = lrelu(asrc[n*2+1] + ad1);
  // pass 1: max
  float m0 = -1e30f, m1 = -1e30f;
  for (int i = lane; i < deg; i += 64){
    int s = csr[off+i];
    m0 = fmaxf(m0, lrelu(asrc[s*2]   + ad0));
    m1 = fmaxf(m1, lrelu(asrc[s*2+1] + ad1));
  }
  #pragma unroll
  for (int d = 1; d < 64; d <<= 1){
    m0 = fmaxf(m0, __shfl_xor(m0, d));
    m1 = fmaxf(m1, __shfl_xor(m1, d));
  }
  m0 = fmaxf(m0, es0); m1 = fmaxf(m1, es1);
  // pass 2: denom
  float s0 = 0.f, s1 = 0.f;
  for (int i = lane; i < deg; i += 64){
    int s = csr[off+i];
    s0 += __expf(lrelu(asrc[s*2]   + ad0) - m0);
    s1 += __expf(lrelu(asrc[s*2+1] + ad1) - m1);
  }
  #pragma unroll
  for (int d = 1; d < 64; d <<= 1){
    s0 += __shfl_xor(s0, d);
    s1 += __shfl_xor(s1, d);
  }
  s0 += __expf(es0 - m0); s1 += __expf(es1 - m1);
  float inv0 = 1.f/(s0 + 1e-16f), inv1 = 1.f/(s1 + 1e-16f);
  // pass 3: aggregate (self loop = i==-1)
  float acc1 = 0.f, acc2 = 0.f;
  for (int i = -1; i < deg; ++i){
    int s = (i < 0) ? n : csr[off+i];
    float e0 = lrelu(asrc[s*2]   + ad0);
    float e1 = lrelu(asrc[s*2+1] + ad1);
    float al0 = __expf(e0 - m0)*inv0;
    float al1 = __expf(e1 - m1)*inv1;
    const float* hr = hfeat + (size_t)s*96;
    acc1 += hr[lane] * (lane < 48 ? al0 : al1);
    if (lane < 32) acc2 += hr[64+lane]*al1;
  }
  gsh[wv][lane] = acc1;
  if (lane < 32) gsh[wv][64+lane] = acc2;
  __syncthreads();
  if (lane < 48){
    float g = 0.5f*(gsh[wv][lane] + gsh[wv][48+lane]) + bias[lane];
    int b = n / 1000, node = n - b*1000;
    int t = lane >> 2, f = lane & 3;
    xseq[((size_t)(t*64 + b))*4000 + node*4 + f] = g;
  }
}

// ---------------- GEMM1: xw1_part = x_seq[768x4000] @ W_ih1^T[4000x1024], split-K=5 ----------------
__global__ void __launch_bounds__(256) k_gemm1(const float* __restrict__ A, const float* __restrict__ B,
                       float* __restrict__ part){
  __shared__ __align__(16) float As[32*72];
  __shared__ __align__(16) float Bs[32*72];
  int tid = threadIdx.x;
  int tx = tid & 15, ty = tid >> 4;
  int m0 = blockIdx.x*64, n0 = blockIdx.y*64;
  int k0 = blockIdx.z*800;
  float acc[4][4] = {};
  for (int kk = 0; kk < 800; kk += 32){
    #pragma unroll
    for (int l = 0; l < 2; ++l){
      int q = tid + l*256;
      int r = q >> 3, c4 = (q & 7)*4;
      float4 va = *(const float4*)(A + (size_t)(m0+r)*4000 + k0+kk+c4);
      As[(c4+0)*72 + r] = va.x; As[(c4+1)*72 + r] = va.y;
      As[(c4+2)*72 + r] = va.z; As[(c4+3)*72 + r] = va.w;
      float4 vb = *(const float4*)(B + (size_t)(n0+r)*4000 + k0+kk+c4);
      Bs[(c4+0)*72 + r] = vb.x; Bs[(c4+1)*72 + r] = vb.y;
      Bs[(c4+2)*72 + r] = vb.z; Bs[(c4+3)*72 + r] = vb.w;
    }
    __syncthreads();
    #pragma unroll
    for (int k = 0; k < 32; ++k){
      float4 a = *(const float4*)(&As[k*72 + ty*4]);
      float4 b = *(const float4*)(&Bs[k*72 + tx*4]);
      acc[0][0] += a.x*b.x; acc[0][1] += a.x*b.y; acc[0][2] += a.x*b.z; acc[0][3] += a.x*b.w;
      acc[1][0] += a.y*b.x; acc[1][1] += a.y*b.y; acc[1][2] += a.y*b.z; acc[1][3] += a.y*b.w;
      acc[2][0] += a.z*b.x; acc[2][1] += a.z*b.y; acc[2][2] += a.z*b.z; acc[2][3] += a.z*b.w;
      acc[3][0] += a.w*b.x; acc[3][1] += a.w*b.y; acc[3][2] += a.w*b.z; acc[3][3] += a.w*b.w;
    }
    __syncthreads();
  }
  #pragma unroll
  for (int i = 0; i < 4; ++i){
    float4 v; v.x = acc[i][0]; v.y = acc[i][1]; v.z = acc[i][2]; v.w = acc[i][3];
    *(float4*)(part + ((size_t)blockIdx.z*768 + m0 + ty*4 + i)*1024 + n0 + tx*4) = v;
  }
}

__global__ void k_reduce1(const float* __restrict__ part, const float* __restrict__ b1,
                          float* __restrict__ xw1){
  int i = blockIdx.x*256 + threadIdx.x;      // 786432 total
  int j = i & 1023;
  float v = b1[j];
  #pragma unroll
  for (int s = 0; s < 5; ++s) v += part[(size_t)s*786432 + i];
  xw1[i] = v;
}

// ---------------- LSTM1 step (2 batches/block) ----------------
__global__ void __launch_bounds__(256) k_step1(const float* __restrict__ xw1, const float* __restrict__ Whh,
                       float* __restrict__ h1, float* __restrict__ c1, float* __restrict__ y1, int t){
  __shared__ __align__(16) float hs[2][256];
  int k = threadIdx.x;
  int b0 = blockIdx.x*2;
  hs[0][k] = h1[(size_t)b0*256 + k];
  hs[1][k] = h1[(size_t)(b0+1)*256 + k];
  __syncthreads();
  const float* xr0 = xw1 + ((size_t)t*64 + b0)*1024;
  const float* xr1 = xr0 + 1024;
  float g[2][4];
  #pragma unroll
  for (int gi = 0; gi < 4; ++gi){
    const float4* wr = (const float4*)(Whh + (size_t)(gi*256 + k)*256);
    const float4* hv0 = (const float4*)hs[0];
    const float4* hv1 = (const float4*)hs[1];
    float d0 = 0.f, d1 = 0.f;
    for (int q = 0; q < 64; ++q){
      float4 wv = wr[q];
      float4 a = hv0[q], b = hv1[q];
      d0 += wv.x*a.x + wv.y*a.y + wv.z*a.z + wv.w*a.w;
      d1 += wv.x*b.x + wv.y*b.y + wv.z*b.z + wv.w*b.w;
    }
    g[0][gi] = xr0[gi*256 + k] + d0;
    g[1][gi] = xr1[gi*256 + k] + d1;
  }
  #pragma unroll
  for (int bb = 0; bb < 2; ++bb){
    int b = b0 + bb;
    float i_ = sigmoidf_(g[bb][0]);
    float f_ = sigmoidf_(g[bb][1]);
    float gg = tanhf(g[bb][2]);
    float o_ = sigmoidf_(g[bb][3]);
    float c = f_*c1[(size_t)b*256 + k] + i_*gg;
    float h = o_*tanhf(c);
    c1[(size_t)b*256 + k] = c;
    h1[(size_t)b*256 + k] = h;
    y1[((size_t)t*64 + b)*256 + k] = h;
  }
}

// ---------------- GEMM2: xw2 = y1[768x256] @ W_ih2^T[256x512] + b2 ----------------
__global__ void __launch_bounds__(256) k_gemm2(const float* __restrict__ y1, const float* __restrict__ W,
                       const float* __restrict__ b2, float* __restrict__ xw2){
  int j = blockIdx.x*16 + (threadIdx.x & 15);
  int m = blockIdx.y*16 + (threadIdx.x >> 4);
  const float4* a = (const float4*)(y1 + (size_t)m*256);
  const float4* w = (const float4*)(W  + (size_t)j*256);
  float d = 0.f;
  for (int q = 0; q < 64; ++q){
    float4 av = a[q], wv = w[q];
    d += av.x*wv.x + av.y*wv.y + av.z*wv.z + av.w*wv.w;
  }
  xw2[(size_t)m*512 + j] = d + b2[j];
}

// ---------------- LSTM2 step (4 batches/block) ----------------
__global__ void __launch_bounds__(128) k_step2(const float* __restrict__ xw2, const float* __restrict__ Whh,
                       float* __restrict__ h2, float* __restrict__ c2, int t){
  __shared__ __align__(16) float hs[4][128];
  int k = threadIdx.x;
  int b0 = blockIdx.x*4;
  #pragma unroll
  for (int bb = 0; bb < 4; ++bb) hs[bb][k] = h2[(size_t)(b0+bb)*128 + k];
  __syncthreads();
  float g[4][4];
  #pragma unroll
  for (int gi = 0; gi < 4; ++gi){
    const float4* wr = (const float4*)(Whh + (size_t)(gi*128 + k)*128);
    float d[4] = {0.f,0.f,0.f,0.f};
    for (int q = 0; q < 32; ++q){
      float4 wv = wr[q];
      #pragma unroll
      for (int bb = 0; bb < 4; ++bb){
        float4 a = ((const float4*)hs[bb])[q];
        d[bb] += wv.x*a.x + wv.y*a.y + wv.z*a.z + wv.w*a.w;
      }
    }
    #pragma unroll
    for (int bb = 0; bb < 4; ++bb)
      g[bb][gi] = xw2[((size_t)t*64 + b0+bb)*512 + gi*128 + k] + d[bb];
  }
  #pragma unroll
  for (int bb = 0; bb < 4; ++bb){
    int b = b0 + bb;
    float i_ = sigmoidf_(g[bb][0]);
    float f_ = sigmoidf_(g[bb][1]);
    float gg = tanhf(g[bb][2]);
    float o_ = sigmoidf_(g[bb][3]);
    float c = f_*c2[(size_t)b*128 + k] + i_*gg;
    float h = o_*tanhf(c);
    c2[(size_t)b*128 + k] = c;
    h2[(size_t)b*128 + k] = h;
  }
}

// ---------------- output projection ----------------
__global__ void __launch_bounds__(256) k_out(const float* __restrict__ h2, const float* __restrict__ Wout,
                     const float* __restrict__ bout, float* __restrict__ out){
  __shared__ __align__(16) float hs[128];
  int b = blockIdx.y;
  if (threadIdx.x < 128) hs[threadIdx.x] = h2[(size_t)b*128 + threadIdx.x];
  __syncthreads();
  int j = blockIdx.x*256 + threadIdx.x;
  if (j >= 2000) return;
  const float4* w = (const float4*)(Wout + (size_t)j*128);
  const float4* hv = (const float4*)hs;
  float d = 0.f;
  for (int q = 0; q < 32; ++q){
    float4 a = hv[q], wv = w[q];
    d += a.x*wv.x + a.y*wv.y + a.z*wv.z + a.w*wv.w;
  }
  out[(size_t)b*2000 + j] = d + bout[j];
}

extern "C" void kernel_launch(void* const* d_in, const int* in_sizes, int n_in,
                              void* d_out, int out_size, void* d_ws, size_t ws_size,
                              hipStream_t stream){
  const float* x     = (const float*)d_in[0];
  const int*   ei    = (const int*)d_in[1];
  const float* Wg    = (const float*)d_in[2];
  const float* att_s = (const float*)d_in[3];
  const float* att_d = (const float*)d_in[4];
  const float* gb    = (const float*)d_in[5];
  const float* Wih1  = (const float*)d_in[6];
  const float* Whh1  = (const float*)d_in[7];
  const float* b1    = (const float*)d_in[8];
  const float* Wih2  = (const float*)d_in[9];
  const float* Whh2  = (const float*)d_in[10];
  const float* b2    = (const float*)d_in[11];
  const float* Wout  = (const float*)d_in[12];
  const float* bout  = (const float*)d_in[13];
  float* out = (float*)d_out;

  char* w = (char*)d_ws;
  float* xseq  = (float*)(w);                         // 12,288,000 B
  char*  hbase = w + 12288000;                        // 24,576,000 B region
  float* hfeat = (float*)hbase;                       // 64000*96*4 = 24,576,000 B
  // aliases inside the hfeat region, live only AFTER k_node finished reading hfeat:
  float* part  = (float*)(hbase);                     // 15,728,640
  float* xw1   = (float*)(hbase + 15728640);          //  3,145,728
  float* y1    = (float*)(hbase + 18874368);          //    786,432
  float* xw2   = (float*)(hbase + 19660800);          //  1,572,864
  float* h1    = (float*)(hbase + 21233664);          //     65,536
  float* c1    = (float*)(hbase + 21299200);          //     65,536
  float* h2    = (float*)(hbase + 21364736);          //     32,768
  float* c2    = (float*)(hbase + 21397504);          //     32,768
  char*  p2 = w + 12288000 + 24576000;
  float* asrc   = (float*)(p2);
  float* adst   = (float*)(p2 + 512000);
  int*   cnt    = (int*)(p2 + 1024000);
  int*   offs   = (int*)(p2 + 1280000);
  int*   cursor = (int*)(p2 + 1536256);
  int*   csr    = (int*)(p2 + 1792256);               // 4,096,000 -> total ~42.8 MB

  hipMemsetAsync(cnt, 0, 64000*sizeof(int), stream);

  k_gat_h<<<250, 256, 0, stream>>>(x, Wg, att_s, att_d, hfeat, asrc, adst);
  k_count<<<4000, 256, 0, stream>>>(ei, cnt);
  k_scan<<<1, 1024, 0, stream>>>(cnt, offs, cursor, NTOT);
  k_scatter<<<4000, 256, 0, stream>>>(ei, cursor, csr);
  k_node<<<16000, 256, 0, stream>>>(hfeat, asrc, adst, offs, csr, gb, xseq);

  // Zero LSTM states ONLY after k_node: h1/c1/h2/c2 alias the hfeat region,
  // which k_gat_h overwrites. (Round-1 bug: memset was issued before k_gat_h,
  // so the LSTM started from GAT features instead of h0=c0=0.)
  hipMemsetAsync(h1, 0, 196608, stream);              // h1,c1,h2,c2 contiguous

  k_gemm1<<<dim3(12,16,5), 256, 0, stream>>>(xseq, Wih1, part);
  k_reduce1<<<3072, 256, 0, stream>>>(part, b1, xw1);
  for (int t = 0; t < NSEQ; ++t)
    k_step1<<<32, 256, 0, stream>>>(xw1, Whh1, h1, c1, y1, t);

  k_gemm2<<<dim3(32,48), 256, 0, stream>>>(y1, Wih2, b2, xw2);
  for (int t = 0; t < NSEQ; ++t)
    k_step2<<<16, 128, 0, stream>>>(xw2, Whh2, h2, c2, t);

  k_out<<<dim3(8,64), 256, 0, stream>>>(h2, Wout, bout, out);
}

// Round 3
// 1064.886 us; speedup vs baseline: 1.7380x; 1.7380x over previous
//
#include <hip/hip_runtime.h>
#include <math.h>

#define NTOT   64000
#define NNODE  1000
#define NBATCH 64
#define NSEQ   12
#define NE     1024000

__device__ __forceinline__ float lrelu(float x){ return x > 0.f ? x : 0.2f*x; }
__device__ __forceinline__ float sigmoidf_(float x){ return 1.f/(1.f+__expf(-x)); }

// ---------------- GAT: h = x @ W_gat, per-node attention scalars ----------------
__global__ void __launch_bounds__(256) k_gat_h(const float* __restrict__ x, const float* __restrict__ Wg,
                       const float* __restrict__ att_s, const float* __restrict__ att_d,
                       float* __restrict__ hfeat, float* __restrict__ asrc, float* __restrict__ adst){
  __shared__ __align__(16) float Ws[48*96];
  __shared__ float as_s[96], ad_s[96];
  for (int i = threadIdx.x; i < 48*96; i += 256) Ws[i] = Wg[i];
  if (threadIdx.x < 96){ as_s[threadIdx.x] = att_s[threadIdx.x]; ad_s[threadIdx.x] = att_d[threadIdx.x]; }
  __syncthreads();
  int n = blockIdx.x * 256 + threadIdx.x;
  if (n >= NTOT) return;
  float xr[48];
  const float4* xv = (const float4*)(x + (size_t)n*48);
  #pragma unroll
  for (int q = 0; q < 12; ++q){ float4 v = xv[q]; xr[q*4]=v.x; xr[q*4+1]=v.y; xr[q*4+2]=v.z; xr[q*4+3]=v.w; }
  float a0=0.f,a1=0.f,d0=0.f,d1=0.f;
  float* hrow = hfeat + (size_t)n*96;
  for (int j = 0; j < 96; ++j){
    float acc = 0.f;
    #pragma unroll
    for (int k = 0; k < 48; ++k) acc += xr[k]*Ws[k*96+j];
    hrow[j] = acc;
    if (j < 48){ a0 += acc*as_s[j]; d0 += acc*ad_s[j]; }
    else       { a1 += acc*as_s[j]; d1 += acc*ad_s[j]; }
  }
  asrc[n*2]=a0; asrc[n*2+1]=a1; adst[n*2]=d0; adst[n*2+1]=d1;
}

// ---------------- CSR build ----------------
__global__ void k_count(const int* __restrict__ ei, int* __restrict__ cnt){
  int e = blockIdx.x*256 + threadIdx.x;
  if (e < NE) atomicAdd(&cnt[ei[NE + e]], 1);
}

// 3-phase parallel scan: wave sums -> scan of 1000 sums -> local rescan
__global__ void __launch_bounds__(256) k_scan1(const int* __restrict__ cnt, int* __restrict__ wsum){
  int w = (blockIdx.x*256 + threadIdx.x) >> 6;
  int lane = threadIdx.x & 63;
  int v = cnt[w*64 + lane];
  int t = v;
  #pragma unroll
  for (int d = 1; d < 64; d <<= 1) t += __shfl_xor(t, d);
  if (lane == 0) wsum[w] = t;
}

__global__ void __launch_bounds__(1024) k_scan2(int* __restrict__ wsum){
  __shared__ int tmp[1024];
  int k = threadIdx.x;
  int v = (k < 1000) ? wsum[k] : 0;
  tmp[k] = v; __syncthreads();
  for (int d = 1; d < 1024; d <<= 1){
    int t = (k >= d) ? tmp[k-d] : 0;
    __syncthreads();
    tmp[k] += t;
    __syncthreads();
  }
  if (k < 1000) wsum[k] = tmp[k] - v;   // exclusive prefix of wave sums
}

__global__ void __launch_bounds__(256) k_scan3(const int* __restrict__ cnt, const int* __restrict__ wpre,
                                               int* __restrict__ offs, int* __restrict__ cursor){
  int w = (blockIdx.x*256 + threadIdx.x) >> 6;
  int lane = threadIdx.x & 63;
  int i = w*64 + lane;
  int v = cnt[i];
  int x = v;
  #pragma unroll
  for (int d = 1; d < 64; d <<= 1){
    int t = __shfl_up(x, d);
    if (lane >= d) x += t;
  }
  int excl = wpre[w] + x - v;
  offs[i] = excl; cursor[i] = excl;
  if (i == NTOT-1) offs[NTOT] = excl + v;
}

__global__ void k_scatter(const int* __restrict__ ei, int* __restrict__ cursor, int* __restrict__ csr){
  int e = blockIdx.x*256 + threadIdx.x;
  if (e < NE){
    int d = ei[NE + e], s = ei[e];
    int pos = atomicAdd(&cursor[d], 1);
    csr[pos] = s;
  }
}

// ---------------- per-node softmax + aggregation + scatter into x_seq ----------------
// no-max-subtraction softmax (logits bounded ~1); denom pass + unroll-4 aggregate
__global__ void __launch_bounds__(256) k_node(const float* __restrict__ hfeat, const float* __restrict__ asrc,
                      const float* __restrict__ adst, const int* __restrict__ offs,
                      const int* __restrict__ csr, const float* __restrict__ bias,
                      float* __restrict__ xseq){
  __shared__ float gsh[4][96];
  int wv = threadIdx.x >> 6, lane = threadIdx.x & 63;
  int n = blockIdx.x*4 + wv;
  int off = offs[n], deg = offs[n+1] - off;
  const float2* as2 = (const float2*)asrc;
  float2 adn = ((const float2*)adst)[n];
  float2 asn = as2[n];
  float es0 = __expf(lrelu(asn.x + adn.x));
  float es1 = __expf(lrelu(asn.y + adn.y));
  // denom pass (lane-strided, coalesced csr, float2 asrc gathers)
  float s0 = 0.f, s1 = 0.f;
  for (int i = lane; i < deg; i += 64){
    int s = csr[off+i];
    float2 a = as2[s];
    s0 += __expf(lrelu(a.x + adn.x));
    s1 += __expf(lrelu(a.y + adn.y));
  }
  #pragma unroll
  for (int d = 1; d < 64; d <<= 1){
    s0 += __shfl_xor(s0, d);
    s1 += __shfl_xor(s1, d);
  }
  s0 += es0; s1 += es1;
  float inv0 = 1.f/(s0 + 1e-16f), inv1 = 1.f/(s1 + 1e-16f);
  // aggregate: lanes 0..47 own channel pairs (2l,2l+1); lanes>=48 duplicate low channels (no extra lines)
  int cl = (lane < 48) ? lane : lane - 48;
  float2 acc = make_float2(0.f, 0.f);
  { // self loop
    const float2* hr = (const float2*)(hfeat + (size_t)n*96);
    float2 r = hr[cl];
    float al = (lane < 24) ? es0*inv0 : es1*inv1;
    acc.x += r.x*al; acc.y += r.y*al;
  }
  int i = 0;
  for (; i + 4 <= deg; i += 4){
    int ss[4];
    #pragma unroll
    for (int j = 0; j < 4; ++j) ss[j] = csr[off+i+j];
    float2 aa[4];
    #pragma unroll
    for (int j = 0; j < 4; ++j) aa[j] = as2[ss[j]];
    #pragma unroll
    for (int j = 0; j < 4; ++j){
      const float2* hr = (const float2*)(hfeat + (size_t)ss[j]*96);
      float2 r = hr[cl];
      float w0 = __expf(lrelu(aa[j].x + adn.x));
      float w1 = __expf(lrelu(aa[j].y + adn.y));
      float al = (lane < 24) ? w0*inv0 : w1*inv1;
      acc.x += r.x*al; acc.y += r.y*al;
    }
  }
  for (; i < deg; ++i){
    int s = csr[off+i];
    float2 a = as2[s];
    const float2* hr = (const float2*)(hfeat + (size_t)s*96);
    float2 r = hr[cl];
    float w0 = __expf(lrelu(a.x + adn.x));
    float w1 = __expf(lrelu(a.y + adn.y));
    float al = (lane < 24) ? w0*inv0 : w1*inv1;
    acc.x += r.x*al; acc.y += r.y*al;
  }
  if (lane < 48){ gsh[wv][2*lane] = acc.x; gsh[wv][2*lane+1] = acc.y; }
  __syncthreads();
  if (lane < 48){
    float g = 0.5f*(gsh[wv][lane] + gsh[wv][48+lane]) + bias[lane];
    int b = n / 1000, node = n - b*1000;
    int t = lane >> 2, f = lane & 3;
    xseq[((size_t)(t*64 + b))*4000 + node*4 + f] = g;
  }
}

// ---------------- GEMM1: xw1_part = x_seq[768x4000] @ W_ih1^T[4000x1024], split-K=5 ----------------
__global__ void __launch_bounds__(256) k_gemm1(const float* __restrict__ A, const float* __restrict__ B,
                       float* __restrict__ part){
  __shared__ __align__(16) float As[32*72];
  __shared__ __align__(16) float Bs[32*72];
  int tid = threadIdx.x;
  int tx = tid & 15, ty = tid >> 4;
  int m0 = blockIdx.x*64, n0 = blockIdx.y*64;
  int k0 = blockIdx.z*800;
  float acc[4][4] = {};
  for (int kk = 0; kk < 800; kk += 32){
    #pragma unroll
    for (int l = 0; l < 2; ++l){
      int q = tid + l*256;
      int r = q >> 3, c4 = (q & 7)*4;
      float4 va = *(const float4*)(A + (size_t)(m0+r)*4000 + k0+kk+c4);
      As[(c4+0)*72 + r] = va.x; As[(c4+1)*72 + r] = va.y;
      As[(c4+2)*72 + r] = va.z; As[(c4+3)*72 + r] = va.w;
      float4 vb = *(const float4*)(B + (size_t)(n0+r)*4000 + k0+kk+c4);
      Bs[(c4+0)*72 + r] = vb.x; Bs[(c4+1)*72 + r] = vb.y;
      Bs[(c4+2)*72 + r] = vb.z; Bs[(c4+3)*72 + r] = vb.w;
    }
    __syncthreads();
    #pragma unroll
    for (int k = 0; k < 32; ++k){
      float4 a = *(const float4*)(&As[k*72 + ty*4]);
      float4 b = *(const float4*)(&Bs[k*72 + tx*4]);
      acc[0][0] += a.x*b.x; acc[0][1] += a.x*b.y; acc[0][2] += a.x*b.z; acc[0][3] += a.x*b.w;
      acc[1][0] += a.y*b.x; acc[1][1] += a.y*b.y; acc[1][2] += a.y*b.z; acc[1][3] += a.y*b.w;
      acc[2][0] += a.z*b.x; acc[2][1] += a.z*b.y; acc[2][2] += a.z*b.z; acc[2][3] += a.z*b.w;
      acc[3][0] += a.w*b.x; acc[3][1] += a.w*b.y; acc[3][2] += a.w*b.z; acc[3][3] += a.w*b.w;
    }
    __syncthreads();
  }
  #pragma unroll
  for (int i = 0; i < 4; ++i){
    float4 v; v.x = acc[i][0]; v.y = acc[i][1]; v.z = acc[i][2]; v.w = acc[i][3];
    *(float4*)(part + ((size_t)blockIdx.z*768 + m0 + ty*4 + i)*1024 + n0 + tx*4) = v;
  }
}

__global__ void k_reduce1(const float* __restrict__ part, const float* __restrict__ b1,
                          float* __restrict__ xw1){
  int i = blockIdx.x*256 + threadIdx.x;      // 786432 total
  int j = i & 1023;
  float v = b1[j];
  #pragma unroll
  for (int s = 0; s < 5; ++s) v += part[(size_t)s*786432 + i];
  xw1[i] = v;
}

// ---------------- fused 2-layer LSTM, all 12 steps, 2 batches per block ----------------
__global__ void __launch_bounds__(256) k_lstm(const float* __restrict__ xw1,
        const float* __restrict__ Whh1, const float* __restrict__ Wih2,
        const float* __restrict__ b2, const float* __restrict__ Whh2,
        float* __restrict__ h2out){
  __shared__ __align__(16) float h1s[2][256];
  __shared__ __align__(16) float h2s[2][128];
  __shared__ __align__(16) float p2s[2][512];
  int k = threadIdx.x;
  int b0 = blockIdx.x*2;
  float c1[2] = {0.f, 0.f};
  float c2[2] = {0.f, 0.f};
  h1s[0][k] = 0.f; h1s[1][k] = 0.f;
  if (k < 128){ h2s[0][k] = 0.f; h2s[1][k] = 0.f; }
  __syncthreads();
  for (int t = 0; t < NSEQ; ++t){
    // ---- layer-1 gates: thread k = hidden unit k ----
    float g[2][4];
    #pragma unroll
    for (int gi = 0; gi < 4; ++gi){
      const float4* wr  = (const float4*)(Whh1 + (size_t)(gi*256 + k)*256);
      const float4* hv0 = (const float4*)h1s[0];
      const float4* hv1 = (const float4*)h1s[1];
      float d0 = 0.f, d1 = 0.f;
      #pragma unroll 8
      for (int q = 0; q < 64; ++q){
        float4 w = wr[q], a = hv0[q], b = hv1[q];
        d0 += w.x*a.x + w.y*a.y + w.z*a.z + w.w*a.w;
        d1 += w.x*b.x + w.y*b.y + w.z*b.z + w.w*b.w;
      }
      g[0][gi] = xw1[((size_t)t*64 + b0  )*1024 + gi*256 + k] + d0;
      g[1][gi] = xw1[((size_t)t*64 + b0+1)*1024 + gi*256 + k] + d1;
    }
    float hn[2];
    #pragma unroll
    for (int bb = 0; bb < 2; ++bb){
      float i_ = sigmoidf_(g[bb][0]);
      float f_ = sigmoidf_(g[bb][1]);
      float gg = tanhf(g[bb][2]);
      float o_ = sigmoidf_(g[bb][3]);
      c1[bb] = f_*c1[bb] + i_*gg;
      hn[bb] = o_*tanhf(c1[bb]);
    }
    __syncthreads();
    h1s[0][k] = hn[0]; h1s[1][k] = hn[1];
    __syncthreads();
    // ---- layer-2 input projection: thread k -> rows 2k, 2k+1 ----
    #pragma unroll
    for (int j = 0; j < 2; ++j){
      int row = 2*k + j;
      const float4* wr  = (const float4*)(Wih2 + (size_t)row*256);
      const float4* hv0 = (const float4*)h1s[0];
      const float4* hv1 = (const float4*)h1s[1];
      float d0 = 0.f, d1 = 0.f;
      #pragma unroll 8
      for (int q = 0; q < 64; ++q){
        float4 w = wr[q], a = hv0[q], b = hv1[q];
        d0 += w.x*a.x + w.y*a.y + w.z*a.z + w.w*a.w;
        d1 += w.x*b.x + w.y*b.y + w.z*b.z + w.w*b.w;
      }
      float bias = b2[row];
      p2s[0][row] = d0 + bias;
      p2s[1][row] = d1 + bias;
    }
    __syncthreads();
    // ---- layer-2 gates: threads < 128 ----
    float hn2[2] = {0.f, 0.f};
    if (k < 128){
      float g2[2][4];
      #pragma unroll
      for (int gi = 0; gi < 4; ++gi){
        const float4* wr  = (const float4*)(Whh2 + (size_t)(gi*128 + k)*128);
        const float4* hv0 = (const float4*)h2s[0];
        const float4* hv1 = (const float4*)h2s[1];
        float d0 = 0.f, d1 = 0.f;
        #pragma unroll 8
        for (int q = 0; q < 32; ++q){
          float4 w = wr[q], a = hv0[q], b = hv1[q];
          d0 += w.x*a.x + w.y*a.y + w.z*a.z + w.w*a.w;
          d1 += w.x*b.x + w.y*b.y + w.z*b.z + w.w*b.w;
        }
        g2[0][gi] = p2s[0][gi*128 + k] + d0;
        g2[1][gi] = p2s[1][gi*128 + k] + d1;
      }
      #pragma unroll
      for (int bb = 0; bb < 2; ++bb){
        float i2 = sigmoidf_(g2[bb][0]);
        float f2 = sigmoidf_(g2[bb][1]);
        float gg = tanhf(g2[bb][2]);
        float o2 = sigmoidf_(g2[bb][3]);
        c2[bb] = f2*c2[bb] + i2*gg;
        hn2[bb] = o2*tanhf(c2[bb]);
      }
    }
    __syncthreads();
    if (k < 128){ h2s[0][k] = hn2[0]; h2s[1][k] = hn2[1]; }
    __syncthreads();
  }
  if (k < 128){
    h2out[(size_t)b0*128 + k]     = h2s[0][k];
    h2out[(size_t)(b0+1)*128 + k] = h2s[1][k];
  }
}

// ---------------- output projection ----------------
__global__ void __launch_bounds__(256) k_out(const float* __restrict__ h2, const float* __restrict__ Wout,
                     const float* __restrict__ bout, float* __restrict__ out){
  __shared__ __align__(16) float hs[128];
  int b = blockIdx.y;
  if (threadIdx.x < 128) hs[threadIdx.x] = h2[(size_t)b*128 + threadIdx.x];
  __syncthreads();
  int j = blockIdx.x*256 + threadIdx.x;
  if (j >= 2000) return;
  const float4* w = (const float4*)(Wout + (size_t)j*128);
  const float4* hv = (const float4*)hs;
  float d = 0.f;
  for (int q = 0; q < 32; ++q){
    float4 a = hv[q], wv = w[q];
    d += a.x*wv.x + a.y*wv.y + a.z*wv.z + a.w*wv.w;
  }
  out[(size_t)b*2000 + j] = d + bout[j];
}

extern "C" void kernel_launch(void* const* d_in, const int* in_sizes, int n_in,
                              void* d_out, int out_size, void* d_ws, size_t ws_size,
                              hipStream_t stream){
  const float* x     = (const float*)d_in[0];
  const int*   ei    = (const int*)d_in[1];
  const float* Wg    = (const float*)d_in[2];
  const float* att_s = (const float*)d_in[3];
  const float* att_d = (const float*)d_in[4];
  const float* gb    = (const float*)d_in[5];
  const float* Wih1  = (const float*)d_in[6];
  const float* Whh1  = (const float*)d_in[7];
  const float* b1    = (const float*)d_in[8];
  const float* Wih2  = (const float*)d_in[9];
  const float* Whh2  = (const float*)d_in[10];
  const float* b2    = (const float*)d_in[11];
  const float* Wout  = (const float*)d_in[12];
  const float* bout  = (const float*)d_in[13];
  float* out = (float*)d_out;

  char* w = (char*)d_ws;
  float* xseq  = (float*)(w);                         // 12,288,000 B
  char*  hbase = w + 12288000;                        // hfeat region: 24,576,000 B
  float* hfeat = (float*)hbase;
  // aliases inside hfeat region, live only AFTER k_node finished reading hfeat:
  float* part  = (float*)(hbase);                     // 15,728,640
  float* xw1   = (float*)(hbase + 15728640);          //  3,145,728
  float* h2o   = (float*)(hbase + 18874368);          //     32,768
  char*  p2 = w + 12288000 + 24576000;
  float* asrc   = (float*)(p2);                       //   512,000
  float* adst   = (float*)(p2 + 512000);              //   512,000
  int*   cnt    = (int*)(p2 + 1024000);               //   256,000
  int*   offs   = (int*)(p2 + 1280000);               //   256,004 (padded)
  int*   cursor = (int*)(p2 + 1536256);               //   256,000
  int*   csr    = (int*)(p2 + 1792256);               // 4,096,000 -> total 42,752,256 B
  int*   wsum   = csr;  // 4 KB alias: scan1/2/3 use it BEFORE k_scatter writes csr

  hipMemsetAsync(cnt, 0, NTOT*sizeof(int), stream);

  k_gat_h<<<250, 256, 0, stream>>>(x, Wg, att_s, att_d, hfeat, asrc, adst);
  k_count<<<4000, 256, 0, stream>>>(ei, cnt);
  k_scan1<<<250, 256, 0, stream>>>(cnt, wsum);
  k_scan2<<<1, 1024, 0, stream>>>(wsum);
  k_scan3<<<250, 256, 0, stream>>>(cnt, wsum, offs, cursor);
  k_scatter<<<4000, 256, 0, stream>>>(ei, cursor, csr);
  k_node<<<16000, 256, 0, stream>>>(hfeat, asrc, adst, offs, csr, gb, xseq);

  k_gemm1<<<dim3(12,16,5), 256, 0, stream>>>(xseq, Wih1, part);
  k_reduce1<<<3072, 256, 0, stream>>>(part, b1, xw1);

  k_lstm<<<32, 256, 0, stream>>>(xw1, Whh1, Wih2, b2, Whh2, h2o);

  k_out<<<dim3(8,64), 256, 0, stream>>>(h2o, Wout, bout, out);
}

// Round 4
// 1000.467 us; speedup vs baseline: 1.8500x; 1.0644x over previous
//
#include <hip/hip_runtime.h>
#include <math.h>

#define NTOT   64000
#define NNODE  1000
#define NBATCH 64
#define NSEQ   12
#define NE     1024000
#define NBLK_L 512

__device__ __forceinline__ float lrelu(float x){ return x > 0.f ? x : 0.2f*x; }
__device__ __forceinline__ float sigmoidf_(float x){ return 1.f/(1.f+__expf(-x)); }

// ---------------- GAT: h = x @ W_gat, per-node attention scalars ----------------
__global__ void __launch_bounds__(256) k_gat_h(const float* __restrict__ x, const float* __restrict__ Wg,
                       const float* __restrict__ att_s, const float* __restrict__ att_d,
                       float* __restrict__ hfeat, float* __restrict__ asrc, float* __restrict__ adst){
  __shared__ __align__(16) float Ws[48*96];
  __shared__ float as_s[96], ad_s[96];
  for (int i = threadIdx.x; i < 48*96; i += 256) Ws[i] = Wg[i];
  if (threadIdx.x < 96){ as_s[threadIdx.x] = att_s[threadIdx.x]; ad_s[threadIdx.x] = att_d[threadIdx.x]; }
  __syncthreads();
  int n = blockIdx.x * 256 + threadIdx.x;
  if (n >= NTOT) return;
  float xr[48];
  const float4* xv = (const float4*)(x + (size_t)n*48);
  #pragma unroll
  for (int q = 0; q < 12; ++q){ float4 v = xv[q]; xr[q*4]=v.x; xr[q*4+1]=v.y; xr[q*4+2]=v.z; xr[q*4+3]=v.w; }
  float a0=0.f,a1=0.f,d0=0.f,d1=0.f;
  float* hrow = hfeat + (size_t)n*96;
  for (int j = 0; j < 96; ++j){
    float acc = 0.f;
    #pragma unroll
    for (int k = 0; k < 48; ++k) acc += xr[k]*Ws[k*96+j];
    hrow[j] = acc;
    if (j < 48){ a0 += acc*as_s[j]; d0 += acc*ad_s[j]; }
    else       { a1 += acc*as_s[j]; d1 += acc*ad_s[j]; }
  }
  asrc[n*2]=a0; asrc[n*2+1]=a1; adst[n*2]=d0; adst[n*2+1]=d1;
}

// ---------------- CSR build ----------------
__global__ void k_count(const int* __restrict__ ei, int* __restrict__ cnt){
  int e = blockIdx.x*256 + threadIdx.x;
  if (e < NE) atomicAdd(&cnt[ei[NE + e]], 1);
}

__global__ void __launch_bounds__(256) k_scan1(const int* __restrict__ cnt, int* __restrict__ wsum){
  int w = (blockIdx.x*256 + threadIdx.x) >> 6;
  int lane = threadIdx.x & 63;
  int v = cnt[w*64 + lane];
  int t = v;
  #pragma unroll
  for (int d = 1; d < 64; d <<= 1) t += __shfl_xor(t, d);
  if (lane == 0) wsum[w] = t;
}

__global__ void __launch_bounds__(1024) k_scan2(int* __restrict__ wsum){
  __shared__ int tmp[1024];
  int k = threadIdx.x;
  int v = (k < 1000) ? wsum[k] : 0;
  tmp[k] = v; __syncthreads();
  for (int d = 1; d < 1024; d <<= 1){
    int t = (k >= d) ? tmp[k-d] : 0;
    __syncthreads();
    tmp[k] += t;
    __syncthreads();
  }
  if (k < 1000) wsum[k] = tmp[k] - v;
}

__global__ void __launch_bounds__(256) k_scan3(const int* __restrict__ cnt, const int* __restrict__ wpre,
                                               int* __restrict__ offs, int* __restrict__ cursor){
  int w = (blockIdx.x*256 + threadIdx.x) >> 6;
  int lane = threadIdx.x & 63;
  int i = w*64 + lane;
  int v = cnt[i];
  int x = v;
  #pragma unroll
  for (int d = 1; d < 64; d <<= 1){
    int t = __shfl_up(x, d);
    if (lane >= d) x += t;
  }
  int excl = wpre[w] + x - v;
  offs[i] = excl; cursor[i] = excl;
  if (i == NTOT-1) offs[NTOT] = excl + v;
}

__global__ void k_scatter(const int* __restrict__ ei, int* __restrict__ cursor, int* __restrict__ csr){
  int e = blockIdx.x*256 + threadIdx.x;
  if (e < NE){
    int d = ei[NE + e], s = ei[e];
    int pos = atomicAdd(&cursor[d], 1);
    csr[pos] = s;
  }
}

// ---------------- per-node softmax + aggregation + scatter into x_seq ----------------
__global__ void __launch_bounds__(256) k_node(const float* __restrict__ hfeat, const float* __restrict__ asrc,
                      const float* __restrict__ adst, const int* __restrict__ offs,
                      const int* __restrict__ csr, const float* __restrict__ bias,
                      float* __restrict__ xseq){
  __shared__ float gsh[4][96];
  int wv = threadIdx.x >> 6, lane = threadIdx.x & 63;
  int n = blockIdx.x*4 + wv;
  int off = offs[n], deg = offs[n+1] - off;
  const float2* as2 = (const float2*)asrc;
  float2 adn = ((const float2*)adst)[n];
  float2 asn = as2[n];
  float es0 = __expf(lrelu(asn.x + adn.x));
  float es1 = __expf(lrelu(asn.y + adn.y));
  float s0 = 0.f, s1 = 0.f;
  for (int i = lane; i < deg; i += 64){
    int s = csr[off+i];
    float2 a = as2[s];
    s0 += __expf(lrelu(a.x + adn.x));
    s1 += __expf(lrelu(a.y + adn.y));
  }
  #pragma unroll
  for (int d = 1; d < 64; d <<= 1){
    s0 += __shfl_xor(s0, d);
    s1 += __shfl_xor(s1, d);
  }
  s0 += es0; s1 += es1;
  float inv0 = 1.f/(s0 + 1e-16f), inv1 = 1.f/(s1 + 1e-16f);
  int cl = (lane < 48) ? lane : lane - 48;
  float2 acc = make_float2(0.f, 0.f);
  {
    const float2* hr = (const float2*)(hfeat + (size_t)n*96);
    float2 r = hr[cl];
    float al = (lane < 24) ? es0*inv0 : es1*inv1;
    acc.x += r.x*al; acc.y += r.y*al;
  }
  int i = 0;
  for (; i + 4 <= deg; i += 4){
    int ss[4];
    #pragma unroll
    for (int j = 0; j < 4; ++j) ss[j] = csr[off+i+j];
    float2 aa[4];
    #pragma unroll
    for (int j = 0; j < 4; ++j) aa[j] = as2[ss[j]];
    #pragma unroll
    for (int j = 0; j < 4; ++j){
      const float2* hr = (const float2*)(hfeat + (size_t)ss[j]*96);
      float2 r = hr[cl];
      float w0 = __expf(lrelu(aa[j].x + adn.x));
      float w1 = __expf(lrelu(aa[j].y + adn.y));
      float al = (lane < 24) ? w0*inv0 : w1*inv1;
      acc.x += r.x*al; acc.y += r.y*al;
    }
  }
  for (; i < deg; ++i){
    int s = csr[off+i];
    float2 a = as2[s];
    const float2* hr = (const float2*)(hfeat + (size_t)s*96);
    float2 r = hr[cl];
    float w0 = __expf(lrelu(a.x + adn.x));
    float w1 = __expf(lrelu(a.y + adn.y));
    float al = (lane < 24) ? w0*inv0 : w1*inv1;
    acc.x += r.x*al; acc.y += r.y*al;
  }
  if (lane < 48){ gsh[wv][2*lane] = acc.x; gsh[wv][2*lane+1] = acc.y; }
  __syncthreads();
  if (lane < 48){
    float g = 0.5f*(gsh[wv][lane] + gsh[wv][48+lane]) + bias[lane];
    int b = n / 1000, node = n - b*1000;
    int t = lane >> 2, f = lane & 3;
    xseq[((size_t)(t*64 + b))*4000 + node*4 + f] = g;
  }
}

// ---------------- GEMM1: xw1_part = x_seq[768x4000] @ W_ih1^T[4000x1024], split-K=5 ----------------
__global__ void __launch_bounds__(256) k_gemm1(const float* __restrict__ A, const float* __restrict__ B,
                       float* __restrict__ part){
  __shared__ __align__(16) float As[32*72];
  __shared__ __align__(16) float Bs[32*72];
  int tid = threadIdx.x;
  int tx = tid & 15, ty = tid >> 4;
  int m0 = blockIdx.x*64, n0 = blockIdx.y*64;
  int k0 = blockIdx.z*800;
  float acc[4][4] = {};
  for (int kk = 0; kk < 800; kk += 32){
    #pragma unroll
    for (int l = 0; l < 2; ++l){
      int q = tid + l*256;
      int r = q >> 3, c4 = (q & 7)*4;
      float4 va = *(const float4*)(A + (size_t)(m0+r)*4000 + k0+kk+c4);
      As[(c4+0)*72 + r] = va.x; As[(c4+1)*72 + r] = va.y;
      As[(c4+2)*72 + r] = va.z; As[(c4+3)*72 + r] = va.w;
      float4 vb = *(const float4*)(B + (size_t)(n0+r)*4000 + k0+kk+c4);
      Bs[(c4+0)*72 + r] = vb.x; Bs[(c4+1)*72 + r] = vb.y;
      Bs[(c4+2)*72 + r] = vb.z; Bs[(c4+3)*72 + r] = vb.w;
    }
    __syncthreads();
    #pragma unroll
    for (int k = 0; k < 32; ++k){
      float4 a = *(const float4*)(&As[k*72 + ty*4]);
      float4 b = *(const float4*)(&Bs[k*72 + tx*4]);
      acc[0][0] += a.x*b.x; acc[0][1] += a.x*b.y; acc[0][2] += a.x*b.z; acc[0][3] += a.x*b.w;
      acc[1][0] += a.y*b.x; acc[1][1] += a.y*b.y; acc[1][2] += a.y*b.z; acc[1][3] += a.y*b.w;
      acc[2][0] += a.z*b.x; acc[2][1] += a.z*b.y; acc[2][2] += a.z*b.z; acc[2][3] += a.z*b.w;
      acc[3][0] += a.w*b.x; acc[3][1] += a.w*b.y; acc[3][2] += a.w*b.z; acc[3][3] += a.w*b.w;
    }
    __syncthreads();
  }
  #pragma unroll
  for (int i = 0; i < 4; ++i){
    float4 v; v.x = acc[i][0]; v.y = acc[i][1]; v.z = acc[i][2]; v.w = acc[i][3];
    *(float4*)(part + ((size_t)blockIdx.z*768 + m0 + ty*4 + i)*1024 + n0 + tx*4) = v;
  }
}

__global__ void k_reduce1(const float* __restrict__ part, const float* __restrict__ b1,
                          float* __restrict__ xw1){
  int i = blockIdx.x*256 + threadIdx.x;
  int j = i & 1023;
  float v = b1[j];
  #pragma unroll
  for (int s = 0; s < 5; ++s) v += part[(size_t)s*786432 + i];
  xw1[i] = v;
}

// ---------------- weight transposes (K-major for coalesced k_lstm dots) ----------------
__global__ void __launch_bounds__(256) k_tr(const float* __restrict__ Whh1, const float* __restrict__ Wih2,
                    const float* __restrict__ Whh2, const float* __restrict__ Wout,
                    float* __restrict__ dst){
  int i = blockIdx.x*256 + threadIdx.x;
  if (i < 262144){ int q = i>>10, r = i&1023; dst[i] = Whh1[r*256+q]; return; }
  i -= 262144;
  if (i < 131072){ int q = i>>9, r = i&511; dst[262144+i] = Wih2[r*256+q]; return; }
  i -= 131072;
  if (i < 65536){ int q = i>>9, r = i&511; dst[393216+i] = Whh2[(size_t)r*128+q]; return; }
  i -= 65536;
  if (i < 256000){ int q = i/2000, r = i - q*2000; dst[458752+i] = Wout[(size_t)r*128+q]; }
}

// ---------------- device-wide barrier ----------------
__device__ __forceinline__ void gbar(int* cnt, int* gen){
  __syncthreads();
  if (threadIdx.x == 0){
    __threadfence();
    int g = atomicAdd(gen, 0);
    if (atomicAdd(cnt, 1) == NBLK_L - 1){
      atomicExch(cnt, 0);
      __threadfence();
      atomicAdd(gen, 1);
    } else {
      while (atomicAdd(gen, 0) == g){ __builtin_amdgcn_s_sleep(2); }
    }
    __threadfence();
  }
  __syncthreads();
}

// ---------------- fused 2-layer LSTM + output projection, persistent grid ----------------
// 512 blocks = 32 batch-pairs x 16 unit-slices. Pipelined: phase k runs layer1(t=k)
// and layer2(t=k-1) on double-buffered h1g/h2g. 13 phases + init barrier + out-proj.
__global__ void __launch_bounds__(256, 2) k_lstm(
    const float* __restrict__ xw1, const float* __restrict__ Wt1,
    const float* __restrict__ Wt2i, const float* __restrict__ Wt2h,
    const float* __restrict__ b2, const float* __restrict__ Wt_o,
    const float* __restrict__ bout,
    float* __restrict__ h1g, float* __restrict__ h2g,
    int* __restrict__ bar, float* __restrict__ out){
  __shared__ float h1s[2][256];
  __shared__ float h2s[2][128];
  __shared__ __align__(16) float pA[256][4];
  __shared__ __align__(16) float pB[256][4];
  int t = threadIdx.x;
  int bg = blockIdx.x >> 4, s = blockIdx.x & 15;
  int b0 = bg*2;
  // zero-init h1'( -1 ), h2'( -1 ) slices (parity buffer 0)
  if (t < 32) h1g[(size_t)(b0 + (t>>4))*256 + s*16 + (t&15)] = 0.f;
  if (t < 16) h2g[(size_t)(b0 + (t>>3))*128 + s*8 + (t&7)] = 0.f;
  float c1r = 0.f;   // owned by threads t<32: (bb = t>>4, u = s*16 + (t&15))
  float c2r = 0.f;   // owned by threads 32..47: (bb = (t-32)>>3, u = s*8 + ((t-32)&7))
  gbar(bar, bar+1);

  // A-dot thread mapping (layer1): kc = t>>5 (8 K-chunks of 32), p = t&31:
  //   gi = p>>3, up = p&7 -> rows r0 = gi*256 + s*16 + 2*up, r0+1
  int kcA = t >> 5, pApx = t & 31;
  int r0A = (pApx >> 3)*256 + s*16 + 2*(pApx & 7);
  // B-dot mapping (layer2): kc2 = t>>4 (16 chunks), p2 = t&15:
  //   gi = p2>>2, up = p2&3 -> rows r0 = gi*128 + s*8 + 2*up, r0+1
  int kcB = t >> 4, pBpx = t & 15;
  int r0B = (pBpx >> 2)*128 + s*8 + 2*(pBpx & 3);

  float* h1f = &h1s[0][0];
  float* h2f = &h2s[0][0];

  for (int k = 0; k <= 12; ++k){
    // ---- stage h1'(k-1), h2'(k-2) ----
    {
      const float* h1src = h1g + (size_t)(k&1)*16384 + (size_t)b0*256;
      const float* h2src = h2g + (size_t)((k+1)&1)*8192 + (size_t)b0*128;
      h1f[t] = h1src[t];
      h1f[t+256] = h1src[t+256];
      h2f[t] = h2src[t];
    }
    __syncthreads();
    // ---- layer1 partial dots (t = A-task), active k<12 ----
    if (k < 12){
      float a0x=0.f, a0y=0.f, a1x=0.f, a1y=0.f;
      const float* wp = Wt1 + (size_t)(kcA*32)*1024 + r0A;
      const float* hb = &h1s[0][kcA*32];
      #pragma unroll 8
      for (int q = 0; q < 32; ++q){
        float2 w = *(const float2*)(wp + (size_t)q*1024);
        float hq0 = hb[q], hq1 = hb[256+q];
        a0x += w.x*hq0; a0y += w.y*hq0;
        a1x += w.x*hq1; a1y += w.y*hq1;
      }
      float4 v; v.x=a0x; v.y=a0y; v.z=a1x; v.w=a1y;
      *(float4*)pA[t] = v;
    }
    // ---- layer2 partial dots (ih over h1'(k-1), hh over h2'(k-2)), active k>=1 ----
    if (k >= 1){
      float q0x=0.f, q0y=0.f, q1x=0.f, q1y=0.f;
      const float* wi = Wt2i + (size_t)(kcB*16)*512 + r0B;
      const float* hb1 = &h1s[0][kcB*16];
      #pragma unroll 8
      for (int q = 0; q < 16; ++q){
        float2 w = *(const float2*)(wi + (size_t)q*512);
        float hq0 = hb1[q], hq1 = hb1[256+q];
        q0x += w.x*hq0; q0y += w.y*hq0;
        q1x += w.x*hq1; q1y += w.y*hq1;
      }
      const float* wh = Wt2h + (size_t)(kcB*8)*512 + r0B;
      const float* hb2 = &h2s[0][kcB*8];
      #pragma unroll 8
      for (int q = 0; q < 8; ++q){
        float2 w = *(const float2*)(wh + (size_t)q*512);
        float hq0 = hb2[q], hq1 = hb2[128+q];
        q0x += w.x*hq0; q0y += w.y*hq0;
        q1x += w.x*hq1; q1y += w.y*hq1;
      }
      float4 v; v.x=q0x; v.y=q0y; v.z=q1x; v.w=q1y;
      *(float4*)pB[t] = v;
    }
    __syncthreads();
    // ---- layer1 unit update (threads 0..31) ----
    if (k < 12 && t < 32){
      int bb = t >> 4, j = t & 15;
      int u = s*16 + j;
      float xg[4];
      #pragma unroll
      for (int gi = 0; gi < 4; ++gi)
        xg[gi] = xw1[((size_t)k*64 + b0+bb)*1024 + gi*256 + u];
      float g[4];
      #pragma unroll
      for (int gi = 0; gi < 4; ++gi){
        int p = gi*8 + (j>>1);
        int e = bb*2 + (j&1);
        float sum = 0.f;
        #pragma unroll
        for (int kc = 0; kc < 8; ++kc) sum += pA[kc*32 + p][e];
        g[gi] = xg[gi] + sum;
      }
      float i_ = sigmoidf_(g[0]);
      float f_ = sigmoidf_(g[1]);
      float gg = tanhf(g[2]);
      float o_ = sigmoidf_(g[3]);
      c1r = f_*c1r + i_*gg;
      float h = o_*tanhf(c1r);
      h1g[(size_t)((k+1)&1)*16384 + (size_t)(b0+bb)*256 + u] = h;
    }
    // ---- layer2 unit update (threads 32..47) ----
    if (k >= 1 && t >= 32 && t < 48){
      int tt = t - 32;
      int bb = tt >> 3, j = tt & 7;
      int u = s*8 + j;
      float bg4[4];
      #pragma unroll
      for (int gi = 0; gi < 4; ++gi) bg4[gi] = b2[gi*128 + u];
      float g[4];
      #pragma unroll
      for (int gi = 0; gi < 4; ++gi){
        int p = gi*4 + (j>>1);
        int e = bb*2 + (j&1);
        float sum = 0.f;
        #pragma unroll
        for (int kc = 0; kc < 16; ++kc) sum += pB[kc*16 + p][e];
        g[gi] = bg4[gi] + sum;
      }
      float i_ = sigmoidf_(g[0]);
      float f_ = sigmoidf_(g[1]);
      float gg = tanhf(g[2]);
      float o_ = sigmoidf_(g[3]);
      c2r = f_*c2r + i_*gg;
      float h = o_*tanhf(c2r);
      h2g[(size_t)(k&1)*8192 + (size_t)(b0+bb)*128 + u] = h;
    }
    gbar(bar, bar+1);
  }

  // ---- output projection: out[b][j] = bout[j] + dot(Wout[j], h2_final) ----
  // h2'(11) lives at parity (11+1)&1 = 0
  {
    const float* h2src = h2g + (size_t)b0*128;
    h2f[t] = h2src[t];
  }
  __syncthreads();
  {
    int bb = t >> 7, i = t & 127;
    if (i < 125){
      int j = s*125 + i;
      float acc = bout[j];
      const float* hb = &h2s[bb][0];
      #pragma unroll 8
      for (int q = 0; q < 128; ++q) acc += hb[q]*Wt_o[(size_t)q*2000 + j];
      out[(size_t)(b0+bb)*2000 + j] = acc;
    }
  }
}

extern "C" void kernel_launch(void* const* d_in, const int* in_sizes, int n_in,
                              void* d_out, int out_size, void* d_ws, size_t ws_size,
                              hipStream_t stream){
  const float* x     = (const float*)d_in[0];
  const int*   ei    = (const int*)d_in[1];
  const float* Wg    = (const float*)d_in[2];
  const float* att_s = (const float*)d_in[3];
  const float* att_d = (const float*)d_in[4];
  const float* gb    = (const float*)d_in[5];
  const float* Wih1  = (const float*)d_in[6];
  const float* Whh1  = (const float*)d_in[7];
  const float* b1    = (const float*)d_in[8];
  const float* Wih2  = (const float*)d_in[9];
  const float* Whh2  = (const float*)d_in[10];
  const float* b2    = (const float*)d_in[11];
  const float* Wout  = (const float*)d_in[12];
  const float* bout  = (const float*)d_in[13];
  float* out = (float*)d_out;

  char* w = (char*)d_ws;
  float* xseq  = (float*)(w);                         // 12,288,000 B
  char*  hbase = w + 12288000;                        // hfeat region: 24,576,000 B
  float* hfeat = (float*)hbase;
  // aliases inside hfeat region, live only AFTER k_node finished reading hfeat:
  float* part  = (float*)(hbase);                     // 15,728,640 B (gemm1 out)
  float* xw1   = (float*)(hbase + 15728640);          //  3,145,728 B
  // transposed weights + LSTM state live inside the part region (written after reduce1):
  float* Wt1   = part;                                // 262144 f
  float* Wt2i  = part + 262144;                       // 131072 f
  float* Wt2h  = part + 393216;                       //  65536 f
  float* Wt_o  = part + 458752;                       // 256000 f
  float* h1g   = part + 714752;                       //  32768 f (2 x 64 x 256)
  float* h2g   = part + 747520;                       //  16384 f (2 x 64 x 128)
  char*  p2 = w + 12288000 + 24576000;
  float* asrc   = (float*)(p2);                       //   512,000
  float* adst   = (float*)(p2 + 512000);              //   512,000
  int*   cnt    = (int*)(p2 + 1024000);               //   256,000
  int*   offs   = (int*)(p2 + 1280000);               //   256,004
  int*   cursor = (int*)(p2 + 1536256);               //   256,000
  int*   csr    = (int*)(p2 + 1792256);               // 4,096,000
  int*   bar    = (int*)(p2 + 5888256);               //         8 -> total ~42.75 MB
  int*   wsum   = csr;  // 4 KB alias: scan1/2/3 use it BEFORE k_scatter writes csr

  hipMemsetAsync(cnt, 0, NTOT*sizeof(int), stream);
  hipMemsetAsync(bar, 0, 8, stream);

  k_gat_h<<<250, 256, 0, stream>>>(x, Wg, att_s, att_d, hfeat, asrc, adst);
  k_count<<<4000, 256, 0, stream>>>(ei, cnt);
  k_scan1<<<250, 256, 0, stream>>>(cnt, wsum);
  k_scan2<<<1, 1024, 0, stream>>>(wsum);
  k_scan3<<<250, 256, 0, stream>>>(cnt, wsum, offs, cursor);
  k_scatter<<<4000, 256, 0, stream>>>(ei, cursor, csr);
  k_node<<<16000, 256, 0, stream>>>(hfeat, asrc, adst, offs, csr, gb, xseq);

  k_gemm1<<<dim3(12,16,5), 256, 0, stream>>>(xseq, Wih1, part);
  k_reduce1<<<3072, 256, 0, stream>>>(part, b1, xw1);
  k_tr<<<2792, 256, 0, stream>>>(Whh1, Wih2, Whh2, Wout, Wt1);

  k_lstm<<<NBLK_L, 256, 0, stream>>>(xw1, Wt1, Wt2i, Wt2h, b2, Wt_o, bout,
                                     h1g, h2g, bar, out);
}